// Round 1
// baseline (281.291 us; speedup 1.0000x reference)
//
#include <hip/hip_runtime.h>

// BCE loss reduction over (64,8,65536,1) fp32 pred/true.
// loss = -sum(t*max(log p,-100) + (1-t)*max(log(1-p),-100)) / (H*B)
//      = -sum_bce / 4194304

#define LOG_CLAMP -100.0f

__global__ __launch_bounds__(256) void vertical_loss_kernel(
    const float4* __restrict__ p4,
    const float4* __restrict__ t4,
    float* __restrict__ out,
    int n4, float scale)
{
    int tid    = blockIdx.x * blockDim.x + threadIdx.x;
    int stride = gridDim.x * blockDim.x;

    float sum = 0.0f;
    for (int i = tid; i < n4; i += stride) {
        float4 p = p4[i];
        float4 t = t4[i];

        float lpx = fmaxf(__logf(p.x), LOG_CLAMP);
        float lpy = fmaxf(__logf(p.y), LOG_CLAMP);
        float lpz = fmaxf(__logf(p.z), LOG_CLAMP);
        float lpw = fmaxf(__logf(p.w), LOG_CLAMP);

        // For p in [0.5,1], 1-p is exact (Sterbenz); for small p the term is ~0.
        float lqx = fmaxf(__logf(1.0f - p.x), LOG_CLAMP);
        float lqy = fmaxf(__logf(1.0f - p.y), LOG_CLAMP);
        float lqz = fmaxf(__logf(1.0f - p.z), LOG_CLAMP);
        float lqw = fmaxf(__logf(1.0f - p.w), LOG_CLAMP);

        sum += t.x * lpx + (1.0f - t.x) * lqx;
        sum += t.y * lpy + (1.0f - t.y) * lqy;
        sum += t.z * lpz + (1.0f - t.z) * lqz;
        sum += t.w * lpw + (1.0f - t.w) * lqw;
    }

    // wave (64-lane) reduction
    #pragma unroll
    for (int off = 32; off > 0; off >>= 1)
        sum += __shfl_down(sum, off, 64);

    __shared__ float wsum[4];  // 256 threads = 4 waves
    int wave = threadIdx.x >> 6;
    int lane = threadIdx.x & 63;
    if (lane == 0) wsum[wave] = sum;
    __syncthreads();

    if (threadIdx.x == 0) {
        float s = wsum[0] + wsum[1] + wsum[2] + wsum[3];
        atomicAdd(out, -s * scale);  // device-scope by default on CDNA
    }
}

extern "C" void kernel_launch(void* const* d_in, const int* in_sizes, int n_in,
                              void* d_out, int out_size, void* d_ws, size_t ws_size,
                              hipStream_t stream) {
    const float4* pred = (const float4*)d_in[0];
    const float4* true_ = (const float4*)d_in[1];
    float* out = (float*)d_out;

    int n = in_sizes[0];              // 33,554,432
    int n4 = n / 4;                   // 8,388,608 float4s (n divisible by 4)
    // Normalization: mean over H (65536), sum over b,c, divide by B (64)
    float scale = 1.0f / (65536.0f * 64.0f);

    // Harness re-poisons d_out with 0xAA before every launch — zero it.
    hipMemsetAsync(d_out, 0, sizeof(float), stream);

    // 2048 blocks x 4 waves = 8192 waves -> 32 waves/CU (full occupancy),
    // grid-stride loop, 16 float4-pairs per thread.
    int blocks = 2048;
    vertical_loss_kernel<<<blocks, 256, 0, stream>>>(pred, true_, out, n4, scale);
}